// Round 1
// baseline (1139.858 us; speedup 1.0000x reference)
//
#include <hip/hip_runtime.h>

#define BATCH   4096
#define IN_DIM  256
#define OUT_DIM 256
#define NK      9
#define NB      5

typedef float v4f __attribute__((ext_vector_type(4)));

__global__ __launch_bounds__(256, 2) void kan_fwd(
    const float* __restrict__ x,
    const float* __restrict__ grids,
    const float* __restrict__ coeffs,
    float* __restrict__ y,
    float* __restrict__ acts)
{
    __shared__ float s_basis[IN_DIM][NB];   // 5 KB
    __shared__ float s_yred[4][OUT_DIM];    // 4 KB

    const int b    = blockIdx.x;
    const int tid  = threadIdx.x;
    const int wave = tid >> 6;
    const int lane = tid & 63;

    // ---- per-i basis precompute (i = tid), exact Cox-de-Boor recursion ----
    {
        const int i = tid;
        const float xv = x[(size_t)b * IN_DIM + i];
        float t[NK];
        #pragma unroll
        for (int k = 0; k < NK; ++k) t[k] = grids[i * NK + k];

        float b0[8];
        #pragma unroll
        for (int j = 0; j < 8; ++j)
            b0[j] = (xv >= t[j] && xv < t[j + 1]) ? 1.0f : 0.0f;

        float b1[7];
        #pragma unroll
        for (int j = 0; j < 7; ++j)
            b1[j] = (xv - t[j]) / (t[j + 1] - t[j]) * b0[j]
                  + (t[j + 2] - xv) / (t[j + 2] - t[j + 1]) * b0[j + 1];

        float b2[6];
        #pragma unroll
        for (int j = 0; j < 6; ++j)
            b2[j] = (xv - t[j]) / (t[j + 2] - t[j]) * b1[j]
                  + (t[j + 3] - xv) / (t[j + 3] - t[j + 1]) * b1[j + 1];

        #pragma unroll
        for (int j = 0; j < 5; ++j)
            s_basis[i][j] = (xv - t[j]) / (t[j + 3] - t[j]) * b2[j]
                          + (t[j + 4] - xv) / (t[j + 4] - t[j + 1]) * b2[j + 1];
    }
    __syncthreads();

    // ---- main loop: wave w handles i = 4*ii + w; lane owns o in [4*lane, 4*lane+4) ----
    const int o0 = lane << 2;
    float yacc[4] = {0.f, 0.f, 0.f, 0.f};
    float* acts_b = acts + (size_t)b * IN_DIM * OUT_DIM;

    #pragma unroll 2
    for (int ii = 0; ii < IN_DIM / 4; ++ii) {
        const int i = (ii << 2) + wave;
        // 20 contiguous floats per lane, 80B aligned to 16 -> 5x dwordx4
        const v4f* cp = reinterpret_cast<const v4f*>(coeffs + (size_t)i * OUT_DIM * NB + o0 * NB);
        v4f cf[5];
        #pragma unroll
        for (int c = 0; c < 5; ++c) cf[c] = cp[c];

        float bs[5];
        #pragma unroll
        for (int n = 0; n < 5; ++n) bs[n] = s_basis[i][n];  // wave-uniform broadcast

        v4f out;
        #pragma unroll
        for (int k = 0; k < 4; ++k) {
            float a = 0.f;
            #pragma unroll
            for (int n = 0; n < 5; ++n) {
                const int f = k * 5 + n;
                a = fmaf(bs[n], cf[f >> 2][f & 3], a);
            }
            out[k] = a;
            yacc[k] += a;
        }
        // acts is write-once-never-read: nontemporal keeps coeffs resident in L2
        __builtin_nontemporal_store(out, reinterpret_cast<v4f*>(acts_b + i * OUT_DIM + o0));
    }

    // ---- y[b,:] reduction across the 4 waves (block owns the row; no atomics) ----
    #pragma unroll
    for (int k = 0; k < 4; ++k) s_yred[wave][o0 + k] = yacc[k];
    __syncthreads();

    y[(size_t)b * OUT_DIM + tid] =
        s_yred[0][tid] + s_yred[1][tid] + s_yred[2][tid] + s_yred[3][tid];
}

extern "C" void kernel_launch(void* const* d_in, const int* in_sizes, int n_in,
                              void* d_out, int out_size, void* d_ws, size_t ws_size,
                              hipStream_t stream) {
    const float* x      = (const float*)d_in[0];
    const float* grids  = (const float*)d_in[1];
    const float* coeffs = (const float*)d_in[2];
    float* y    = (float*)d_out;
    float* acts = y + (size_t)BATCH * OUT_DIM;   // tuple order: (y, acts), y first
    kan_fwd<<<dim3(BATCH), dim3(256), 0, stream>>>(x, grids, coeffs, y, acts);
}